// Round 6
// baseline (187.345 us; speedup 1.0000x reference)
//
#include <hip/hip_runtime.h>
#include <hip/hip_bf16.h>
#include <hip/hip_cooperative_groups.h>

namespace cg = cooperative_groups;

// Fused Mamba-2 chunked SSD, one cooperative launch (grid=256 <= CU count so
// the cooperative-occupancy check cannot reject it), with a same-call
// fallback to the proven 3-kernel path if hipLaunchCooperativeKernel errors.
//
// fused_ssd: 256 blocks x 512 threads. Block g owns global chunks 4g..4g+3
// (4 adjacent h, same (b,c) -> shared B/C/B^T tiles). Two 4-wave teams; team
// tm handles sub-chunks 2tm, 2tm+1 with private sXt/sS tiles.
// Phase A: per chunk: cumsum(delta), G=C.B^T, S=mask*exp*G, Yint=S.X kept in
//          registers, Hend0=(w*X)^T.B -> ws.
// Phase B: grid.sync; 1 element/thread (256*512=131072) batched 32-chunk scan
//          -> Hstart in-place + Hlast.
// Phase C: grid.sync; stage Hstart bf16 (reusing team tiles), single store
//          Y = Yint + Lambda_t * C.Hstart.
// MFMA 16x16x32 bf16: A m=lane&15,k=quad*8+j; B n=lane&15,k=quad*8+j;
//                     D col=lane&15, row=quad*4+reg.
// LDS rows padded to 72 bf16 (36 words) to spread b128 reads over banks.

constexpr int BSZ = 2, T = 2048, H = 16, P = 64, N = 64;
constexpr int L = 64, NC = T / L;   // 32 chunks
constexpr int LS = 72;

using bf16x8 = __attribute__((ext_vector_type(8))) short;
using f32x4  = __attribute__((ext_vector_type(4))) float;

__device__ inline ushort f2bf(float f) {
    unsigned u = __float_as_uint(f);
    u += 0x7FFFu + ((u >> 16) & 1u);
    return (ushort)(u >> 16);
}
__device__ inline unsigned pack2(float a, float b) {
    return (unsigned)f2bf(a) | ((unsigned)f2bf(b) << 16);
}
__device__ inline float bf2f(ushort h) {
    return __uint_as_float(((unsigned)h) << 16);
}

// ================= fused cooperative kernel =================
__global__ __launch_bounds__(512, 1) void fused_ssd(
    const float* __restrict__ X, const float* __restrict__ delta,
    const float* __restrict__ Bm, const float* __restrict__ Cm,
    const float* __restrict__ A_log,
    float* __restrict__ Y, float* __restrict__ Hlast,
    float* __restrict__ Hbuf, float* __restrict__ Dchunk)
{
    __shared__ __align__(16) ushort sB [64 * LS];      // [tau][n]
    __shared__ __align__(16) ushort sC [64 * LS];      // [t][n] (persists to C)
    __shared__ __align__(16) ushort sBt[64 * LS];      // [n][tau]
    __shared__ __align__(16) ushort sXt[2][64 * LS];   // per-team [p][tau]
    __shared__ __align__(16) ushort sS [2][64 * LS];   // per-team [t][tau]
    __shared__ float sSa[2][64], sSb[2][64], sW[2][64], sLam[2][2][64];

    const int tid  = threadIdx.x, lane = tid & 63, w = tid >> 6;  // w: 0..7
    const int team = w >> 2,      wv   = w & 3;                   // team wave 0..3
    const int quad = lane >> 4,   l16  = lane & 15;
    const int idx0  = 4 * blockIdx.x;            // chunk ids idx0..idx0+3
    const int hbase = idx0 & (H - 1);            // multiple of 4
    const int c     = (idx0 >> 4) & (NC - 1);
    const int b     = idx0 >> 9;
    const int t0    = c * L;

    // ---- shared staging: B,C tiles + B^T (all 8 waves) ----
    {
        const float4* gB4 = (const float4*)(Bm + ((size_t)b * T + t0) * N);
        const float4* gC4 = (const float4*)(Cm + ((size_t)b * T + t0) * N);
        #pragma unroll
        for (int r = 0; r < 2; ++r) {
            int idx = r * 512 + tid, t = idx >> 4, n4 = (idx & 15) << 2;
            float4 vb = gB4[idx], vc = gC4[idx];
            *(uint2*)&sB[t * LS + n4] = make_uint2(pack2(vb.x, vb.y), pack2(vb.z, vb.w));
            *(uint2*)&sC[t * LS + n4] = make_uint2(pack2(vc.x, vc.y), pack2(vc.z, vc.w));
        }
        const float* gB = Bm + ((size_t)b * T + t0) * N;
        #pragma unroll
        for (int i = 0; i < 4; ++i) {
            int tau = (w * 4 + i) * 2;
            *(unsigned*)&sBt[lane * LS + tau] =
                pack2(gB[(size_t)tau * N + lane], gB[(size_t)(tau + 1) * N + lane]);
        }
    }

    f32x4 ya[2][4];   // Y_intra strips (this team's 2 sub-chunks)

    // ---- Phase A ----
    #pragma unroll
    for (int s = 0; s < 2; ++s) {
        const int h = hbase + 2 * team + s;
        const int chunkid = (b * H + h) * NC + c;

        // X^T tile for this h into the team's tile; team wave wv covers
        // tau in [16wv, 16wv+16)
        {
            const float* gX = X + (((size_t)b * T + t0) * H + h) * P;
            #pragma unroll
            for (int i = 0; i < 8; ++i) {
                int tau = wv * 16 + 2 * i;
                *(unsigned*)&sXt[team][lane * LS + tau] =
                    pack2(gX[(size_t)tau * (H * P) + lane],
                          gX[(size_t)(tau + 1) * (H * P) + lane]);
            }
        }
        if (wv == 0) {
            float dl = delta[((size_t)b * T + t0 + lane) * H + h];
            float sv = -__expf(A_log[h]) * dl;
            #pragma unroll
            for (int off = 1; off < 64; off <<= 1) {
                float u = __shfl_up(sv, off, 64);
                if (lane >= off) sv += u;
            }
            float sL  = __shfl(sv, 63, 64);
            float lnd = __logf(dl);
            sSa[team][lane] = sv;
            sSb[team][lane] = lnd - sv;
            sW [team][lane] = __expf(sL + lnd - sv);
            sLam[team][s][lane] = __expf(sv);
            if (lane == 63) Dchunk[chunkid] = __expf(sL);
        }
        __syncthreads();

        // G strip (rows t in [16wv,16wv+16))
        f32x4 g[4];
        #pragma unroll
        for (int j = 0; j < 4; ++j) g[j] = (f32x4){0.f, 0.f, 0.f, 0.f};
        #pragma unroll
        for (int ks = 0; ks < 2; ++ks) {
            const int ko = ks * 32 + quad * 8;
            bf16x8 af = *(const bf16x8*)&sC[(wv * 16 + l16) * LS + ko];
            #pragma unroll
            for (int jt = 0; jt < 4; ++jt) {
                bf16x8 bfr = *(const bf16x8*)&sB[(jt * 16 + l16) * LS + ko];
                g[jt] = __builtin_amdgcn_mfma_f32_16x16x32_bf16(af, bfr, g[jt], 0, 0, 0);
            }
        }
        // S strip -> bf16 LDS (team tile)
        #pragma unroll
        for (int jt = 0; jt < 4; ++jt) {
            const int tau = jt * 16 + l16;
            const float sbv = sSb[team][tau];
            #pragma unroll
            for (int r = 0; r < 4; ++r) {
                const int t = wv * 16 + quad * 4 + r;
                float arg = (tau <= t) ? (sSa[team][t] + sbv) : -80.0f;
                sS[team][t * LS + tau] = f2bf(__expf(arg) * g[jt][r]);
            }
        }
        __syncthreads();

        // Yint strip (registers) and Hend0 strip (-> ws)
        f32x4 ha[4];
        #pragma unroll
        for (int j = 0; j < 4; ++j) {
            ya[s][j] = (f32x4){0.f, 0.f, 0.f, 0.f};
            ha[j]    = (f32x4){0.f, 0.f, 0.f, 0.f};
        }
        #pragma unroll
        for (int ks = 0; ks < 2; ++ks) {
            const int ko = ks * 32 + quad * 8;
            bf16x8 sa = *(const bf16x8*)&sS [team][(wv * 16 + l16) * LS + ko];
            bf16x8 xa = *(const bf16x8*)&sXt[team][(wv * 16 + l16) * LS + ko];
            union { bf16x8 v; unsigned u[4]; } xw;
            #pragma unroll
            for (int j2 = 0; j2 < 4; ++j2)
                xw.u[j2] = pack2(bf2f((ushort)xa[2*j2])   * sW[team][ko + 2*j2],
                                 bf2f((ushort)xa[2*j2+1]) * sW[team][ko + 2*j2+1]);
            #pragma unroll
            for (int jp = 0; jp < 4; ++jp) {
                bf16x8 xb = *(const bf16x8*)&sXt[team][(jp * 16 + l16) * LS + ko];
                ya[s][jp] = __builtin_amdgcn_mfma_f32_16x16x32_bf16(sa, xb, ya[s][jp], 0, 0, 0);
            }
            #pragma unroll
            for (int jn = 0; jn < 4; ++jn) {
                bf16x8 bb = *(const bf16x8*)&sBt[(jn * 16 + l16) * LS + ko];
                ha[jn] = __builtin_amdgcn_mfma_f32_16x16x32_bf16(xw.v, bb, ha[jn], 0, 0, 0);
            }
        }
        float* Hg = Hbuf + (size_t)chunkid * (P * N);
        #pragma unroll
        for (int jn = 0; jn < 4; ++jn)
            #pragma unroll
            for (int r = 0; r < 4; ++r)
                Hg[(wv * 16 + quad * 4 + r) * N + jn * 16 + l16] = ha[jn][r];
        __syncthreads();
    }

    cg::grid_group grid = cg::this_grid();
    grid.sync();

    // ---- Phase B: chunk scan, exactly 1 element/thread, batched loads ----
    {
        const unsigned gid = blockIdx.x * 512u + tid;   // 131072 = B*H*P*N
        const int bh  = gid >> 12;
        const int rem = gid & 4095;
        float v[NC];
        #pragma unroll
        for (int cc = 0; cc < NC; ++cc)
            v[cc] = Hbuf[((size_t)(bh * NC + cc) << 12) + rem];
        float hs = 0.0f;
        #pragma unroll
        for (int cc = 0; cc < NC; ++cc) {
            const float tmp = v[cc];
            v[cc] = hs;
            hs = Dchunk[bh * NC + cc] * hs + tmp;
        }
        #pragma unroll
        for (int cc = 0; cc < NC; ++cc)
            Hbuf[((size_t)(bh * NC + cc) << 12) + rem] = v[cc];
        Hlast[gid] = hs;
    }
    grid.sync();

    // ---- Phase C: Y = Yint + Lambda * C . Hstart (single store) ----
    #pragma unroll
    for (int s = 0; s < 2; ++s) {
        const int h = hbase + 2 * team + s;
        const int chunkid = (b * H + h) * NC + c;
        ushort* dst = s ? sS[team] : sXt[team];    // reuse team tiles
        const float4* Hg4 = (const float4*)(Hbuf + (size_t)chunkid * (P * N));
        const int ttid = wv * 64 + lane;           // 0..255 within team
        #pragma unroll
        for (int r = 0; r < 4; ++r) {
            int idx = r * 256 + ttid, p = idx >> 4, n4 = (idx & 15) << 2;
            float4 vh = Hg4[idx];
            *(uint2*)&dst[p * LS + n4] = make_uint2(pack2(vh.x, vh.y), pack2(vh.z, vh.w));
        }
    }
    __syncthreads();
    #pragma unroll
    for (int s = 0; s < 2; ++s) {
        const int h = hbase + 2 * team + s;
        const ushort* sH = s ? sS[team] : sXt[team];
        f32x4 acc[4];
        #pragma unroll
        for (int j = 0; j < 4; ++j) acc[j] = (f32x4){0.f, 0.f, 0.f, 0.f};
        #pragma unroll
        for (int ks = 0; ks < 2; ++ks) {
            const int ko = ks * 32 + quad * 8;
            bf16x8 ca = *(const bf16x8*)&sC[(wv * 16 + l16) * LS + ko];
            #pragma unroll
            for (int jp = 0; jp < 4; ++jp) {
                bf16x8 hb = *(const bf16x8*)&sH[(jp * 16 + l16) * LS + ko];
                acc[jp] = __builtin_amdgcn_mfma_f32_16x16x32_bf16(ca, hb, acc[jp], 0, 0, 0);
            }
        }
        float* Yg = Y + (((size_t)b * T + t0) * H + h) * P;
        #pragma unroll
        for (int jp = 0; jp < 4; ++jp)
            #pragma unroll
            for (int r = 0; r < 4; ++r) {
                const int t = wv * 16 + quad * 4 + r;
                Yg[(size_t)t * (H * P) + jp * 16 + l16] =
                    ya[s][jp][r] + sLam[team][s][t] * acc[jp][r];
            }
    }
}

// ================= fallback: round-4 3-kernel path (proven) =================
__global__ __launch_bounds__(256, 3) void p1_intra(
    const float* __restrict__ X, const float* __restrict__ delta,
    const float* __restrict__ Bm, const float* __restrict__ Cm,
    const float* __restrict__ A_log,
    float* __restrict__ Y, float* __restrict__ Hbuf, float* __restrict__ Dchunk)
{
    __shared__ __align__(16) ushort sB [64 * LS];
    __shared__ __align__(16) ushort sC [64 * LS];
    __shared__ __align__(16) ushort sBt[64 * LS];
    __shared__ __align__(16) ushort sXt[64 * LS];
    __shared__ __align__(16) ushort sS [64 * LS];
    __shared__ float sSa[64], sSb[64], sW[64];

    const int tid  = threadIdx.x, lane = tid & 63, w = tid >> 6;
    const int quad = lane >> 4,   l16  = lane & 15;
    const int blk = blockIdx.x;
    const int h   = blk & (H - 1);
    const int c   = (blk >> 4) & (NC - 1);
    const int b   = blk >> 9;
    const int t0  = c * L;
    const int chunkid = (b * H + h) * NC + c;

    {
        const float4* gB4 = (const float4*)(Bm + ((size_t)b * T + t0) * N);
        const float4* gC4 = (const float4*)(Cm + ((size_t)b * T + t0) * N);
        #pragma unroll
        for (int r = 0; r < 4; ++r) {
            int idx = r * 256 + tid, t = idx >> 4, n4 = (idx & 15) << 2;
            float4 vb = gB4[idx], vc = gC4[idx];
            *(uint2*)&sB[t * LS + n4] = make_uint2(pack2(vb.x, vb.y), pack2(vb.z, vb.w));
            *(uint2*)&sC[t * LS + n4] = make_uint2(pack2(vc.x, vc.y), pack2(vc.z, vc.w));
        }
        const float* gB = Bm + ((size_t)b * T + t0) * N;
        #pragma unroll
        for (int i = 0; i < 8; ++i) {
            int tau = (w * 8 + i) * 2;
            *(unsigned*)&sBt[lane * LS + tau] =
                pack2(gB[(size_t)tau * N + lane], gB[(size_t)(tau + 1) * N + lane]);
        }
    }
    {
        const float* gX = X + (((size_t)b * T + t0) * H + h) * P;
        #pragma unroll
        for (int i = 0; i < 8; ++i) {
            int tau = w * 16 + 2 * i;
            *(unsigned*)&sXt[lane * LS + tau] =
                pack2(gX[(size_t)tau * (H * P) + lane],
                      gX[(size_t)(tau + 1) * (H * P) + lane]);
        }
    }
    if (w == 0) {
        float dl = delta[((size_t)b * T + t0 + lane) * H + h];
        float s = -__expf(A_log[h]) * dl;
        #pragma unroll
        for (int off = 1; off < 64; off <<= 1) {
            float u = __shfl_up(s, off, 64);
            if (lane >= off) s += u;
        }
        float sL  = __shfl(s, 63, 64);
        float lnd = __logf(dl);
        sSa[lane] = s;
        sSb[lane] = lnd - s;
        sW [lane] = __expf(sL + lnd - s);
        if (lane == 63) Dchunk[chunkid] = __expf(sL);
    }
    __syncthreads();

    f32x4 g[4];
    #pragma unroll
    for (int j = 0; j < 4; ++j) g[j] = (f32x4){0.f, 0.f, 0.f, 0.f};
    #pragma unroll
    for (int ks = 0; ks < 2; ++ks) {
        const int ko = ks * 32 + quad * 8;
        bf16x8 af = *(const bf16x8*)&sC[(w * 16 + l16) * LS + ko];
        #pragma unroll
        for (int jt = 0; jt < 4; ++jt) {
            bf16x8 bfr = *(const bf16x8*)&sB[(jt * 16 + l16) * LS + ko];
            g[jt] = __builtin_amdgcn_mfma_f32_16x16x32_bf16(af, bfr, g[jt], 0, 0, 0);
        }
    }
    #pragma unroll
    for (int jt = 0; jt < 4; ++jt) {
        const int tau = jt * 16 + l16;
        const float sbv = sSb[tau];
        #pragma unroll
        for (int r = 0; r < 4; ++r) {
            const int t = w * 16 + quad * 4 + r;
            float arg = (tau <= t) ? (sSa[t] + sbv) : -80.0f;
            sS[t * LS + tau] = f2bf(__expf(arg) * g[jt][r]);
        }
    }
    __syncthreads();

    f32x4 ya[4], ha[4];
    #pragma unroll
    for (int j = 0; j < 4; ++j) {
        ya[j] = (f32x4){0.f, 0.f, 0.f, 0.f};
        ha[j] = (f32x4){0.f, 0.f, 0.f, 0.f};
    }
    #pragma unroll
    for (int ks = 0; ks < 2; ++ks) {
        const int ko = ks * 32 + quad * 8;
        bf16x8 sa = *(const bf16x8*)&sS [(w * 16 + l16) * LS + ko];
        bf16x8 xa = *(const bf16x8*)&sXt[(w * 16 + l16) * LS + ko];
        union { bf16x8 v; unsigned u[4]; } xw;
        #pragma unroll
        for (int j2 = 0; j2 < 4; ++j2)
            xw.u[j2] = pack2(bf2f((ushort)xa[2*j2])   * sW[ko + 2*j2],
                             bf2f((ushort)xa[2*j2+1]) * sW[ko + 2*j2+1]);
        #pragma unroll
        for (int jp = 0; jp < 4; ++jp) {
            bf16x8 xb = *(const bf16x8*)&sXt[(jp * 16 + l16) * LS + ko];
            ya[jp] = __builtin_amdgcn_mfma_f32_16x16x32_bf16(sa, xb, ya[jp], 0, 0, 0);
        }
        #pragma unroll
        for (int jn = 0; jn < 4; ++jn) {
            bf16x8 bb = *(const bf16x8*)&sBt[(jn * 16 + l16) * LS + ko];
            ha[jn] = __builtin_amdgcn_mfma_f32_16x16x32_bf16(xw.v, bb, ha[jn], 0, 0, 0);
        }
    }

    float* Yg = Y + (((size_t)b * T + t0) * H + h) * P;
    #pragma unroll
    for (int jp = 0; jp < 4; ++jp)
        #pragma unroll
        for (int r = 0; r < 4; ++r)
            Yg[(size_t)(w * 16 + quad * 4 + r) * (H * P) + jp * 16 + l16] = ya[jp][r];
    float* Hg = Hbuf + (size_t)chunkid * (P * N);
    #pragma unroll
    for (int jn = 0; jn < 4; ++jn)
        #pragma unroll
        for (int r = 0; r < 4; ++r)
            Hg[(w * 16 + quad * 4 + r) * N + jn * 16 + l16] = ha[jn][r];
}

__global__ __launch_bounds__(256, 4) void p2_scan(
    const float* __restrict__ Dchunk, float* __restrict__ Hbuf,
    float* __restrict__ Hlast)
{
    const int bh  = blockIdx.x >> 4;
    const int rem = ((blockIdx.x & 15) << 8) | threadIdx.x;
    float v[NC];
    #pragma unroll
    for (int c = 0; c < NC; ++c)
        v[c] = Hbuf[(((size_t)(bh * NC + c)) << 12) + rem];
    float hs = 0.0f;
    #pragma unroll
    for (int c = 0; c < NC; ++c) {
        const float tmp = v[c];
        v[c] = hs;
        hs = Dchunk[bh * NC + c] * hs + tmp;
    }
    #pragma unroll
    for (int c = 0; c < NC; ++c)
        Hbuf[(((size_t)(bh * NC + c)) << 12) + rem] = v[c];
    Hlast[(size_t)bh * 4096 + rem] = hs;
}

__global__ __launch_bounds__(256, 4) void p3_inter(
    const float* __restrict__ delta, const float* __restrict__ Cm,
    const float* __restrict__ A_log, const float* __restrict__ Hbuf,
    float* __restrict__ Y)
{
    __shared__ __align__(16) ushort sC[64 * LS];
    __shared__ __align__(16) ushort sH[64 * LS];
    __shared__ float sLam[64];

    const int tid  = threadIdx.x, lane = tid & 63, w = tid >> 6;
    const int quad = lane >> 4,   l16  = lane & 15;
    const int blk = blockIdx.x;
    const int h   = blk & (H - 1);
    const int c   = (blk >> 4) & (NC - 1);
    const int b   = blk >> 9;
    const int t0  = c * L;
    const int chunkid = (b * H + h) * NC + c;

    {
        const float4* gC4 = (const float4*)(Cm + ((size_t)b * T + t0) * N);
        const float4* Hg4 = (const float4*)(Hbuf + (size_t)chunkid * (P * N));
        #pragma unroll
        for (int r = 0; r < 4; ++r) {
            int idx = r * 256 + tid, t = idx >> 4, n4 = (idx & 15) << 2;
            float4 vc = gC4[idx];
            float4 vh = Hg4[idx];
            *(uint2*)&sC[t * LS + n4] = make_uint2(pack2(vc.x, vc.y), pack2(vc.z, vc.w));
            *(uint2*)&sH[t * LS + n4] = make_uint2(pack2(vh.x, vh.y), pack2(vh.z, vh.w));
        }
    }
    if (w == 0) {
        float dl = delta[((size_t)b * T + t0 + lane) * H + h];
        float s = -__expf(A_log[h]) * dl;
        #pragma unroll
        for (int off = 1; off < 64; off <<= 1) {
            float u = __shfl_up(s, off, 64);
            if (lane >= off) s += u;
        }
        sLam[lane] = __expf(s);
    }
    __syncthreads();

    f32x4 acc[4];
    #pragma unroll
    for (int j = 0; j < 4; ++j) acc[j] = (f32x4){0.f, 0.f, 0.f, 0.f};
    #pragma unroll
    for (int ks = 0; ks < 2; ++ks) {
        const int ko = ks * 32 + quad * 8;
        bf16x8 ca = *(const bf16x8*)&sC[(w * 16 + l16) * LS + ko];
        #pragma unroll
        for (int jp = 0; jp < 4; ++jp) {
            bf16x8 hb = *(const bf16x8*)&sH[(jp * 16 + l16) * LS + ko];
            acc[jp] = __builtin_amdgcn_mfma_f32_16x16x32_bf16(ca, hb, acc[jp], 0, 0, 0);
        }
    }

    float* Yg = Y + (((size_t)b * T + t0) * H + h) * P;
    #pragma unroll
    for (int jp = 0; jp < 4; ++jp)
        #pragma unroll
        for (int r = 0; r < 4; ++r) {
            const int t = w * 16 + quad * 4 + r;
            const size_t off = (size_t)t * (H * P) + jp * 16 + l16;
            Yg[off] = Yg[off] + sLam[t] * acc[jp][r];
        }
}

extern "C" void kernel_launch(void* const* d_in, const int* in_sizes, int n_in,
                              void* d_out, int out_size, void* d_ws, size_t ws_size,
                              hipStream_t stream) {
    const float* X     = (const float*)d_in[0];
    const float* delta = (const float*)d_in[1];
    const float* Bm    = (const float*)d_in[2];
    const float* Cm    = (const float*)d_in[3];
    const float* A_log = (const float*)d_in[4];

    float* Y     = (float*)d_out;
    float* Hlast = (float*)d_out + (size_t)BSZ * T * H * P;
    float* Hbuf   = (float*)d_ws;
    float* Dchunk = (float*)d_ws + (size_t)BSZ * H * NC * P * N;

    void* args[] = {(void*)&X, (void*)&delta, (void*)&Bm, (void*)&Cm,
                    (void*)&A_log, (void*)&Y, (void*)&Hlast,
                    (void*)&Hbuf, (void*)&Dchunk};
    hipError_t err = hipLaunchCooperativeKernel(
        (const void*)fused_ssd, dim3(BSZ * NC * H / 4), dim3(512),
        args, 0, stream);
    if (err != hipSuccess) {
        (void)hipGetLastError();   // clear sticky error, run proven 3-kernel path
        const int nblk = BSZ * NC * H;   // 1024
        p1_intra<<<nblk, 256, 0, stream>>>(X, delta, Bm, Cm, A_log, Y, Hbuf, Dchunk);
        p2_scan<<<(BSZ * H * P * N) / 256, 256, 0, stream>>>(Dchunk, Hbuf, Hlast);
        p3_inter<<<nblk, 256, 0, stream>>>(delta, Cm, A_log, Hbuf, Y);
    }
}

// Round 7
// 100.341 us; speedup vs baseline: 1.8671x; 1.8671x over previous
//
#include <hip/hip_runtime.h>

// Mamba-2 chunked SSD, 3-kernel path (round-4 structure) with bf16 packed
// intermediates and fully-coalesced stores.
//   P1: per (b,h,c): cumsum(delta); G=C.B^T; S=mask*exp*G; Yint=S.X -> Ybuf
//       (bf16 packed tile); Hend0=(w*X)^T.B -> Hbuf (bf16 packed tile).
//   P2: 32-chunk scan over Hbuf (uint-paired bf16) -> Hstart in place + Hlast.
//   P3: Y = Yint + Lambda_t * C.Hstart  (single fp32 Y store, LDS-restaged
//       so each store instr covers 4 x 256B full rows).
// MFMA 16x16x32 bf16: A m=lane&15,k=quad*8+j; B n=lane&15,k=quad*8+j;
//                     D col=lane&15, row=quad*4+reg.
// LDS rows padded to 72 bf16 (36 words) to spread b128 reads over banks.
// ~47 us of dur_us is the harness's 256 MiB d_ws poison fill (measured r4/r6).

constexpr int BSZ = 2, T = 2048, H = 16, P = 64, N = 64;
constexpr int L = 64, NC = T / L;   // 32 chunks
constexpr int LS = 72;              // LDS row stride (ushorts)
constexpr int FS = 68;              // fp32 LDS row stride (floats)

using bf16x8 = __attribute__((ext_vector_type(8))) short;
using f32x4  = __attribute__((ext_vector_type(4))) float;

__device__ inline ushort f2bf(float f) {
    unsigned u = __float_as_uint(f);
    u += 0x7FFFu + ((u >> 16) & 1u);
    return (ushort)(u >> 16);
}
__device__ inline unsigned pack2(float a, float b) {
    return (unsigned)f2bf(a) | ((unsigned)f2bf(b) << 16);
}
__device__ inline float bf2f(ushort h) {
    return __uint_as_float(((unsigned)h) << 16);
}

// ---------------- P1: intra-chunk ----------------
__global__ __launch_bounds__(256, 3) void p1_intra(
    const float* __restrict__ X, const float* __restrict__ delta,
    const float* __restrict__ Bm, const float* __restrict__ Cm,
    const float* __restrict__ A_log,
    ushort* __restrict__ Ybuf, ushort* __restrict__ Hbuf,
    float* __restrict__ Dchunk)
{
    __shared__ __align__(16) ushort sB [64 * LS];   // [tau][n]
    __shared__ __align__(16) ushort sC [64 * LS];   // [t][n]
    __shared__ __align__(16) ushort sBt[64 * LS];   // [n][tau]
    __shared__ __align__(16) ushort sXt[64 * LS];   // [p][tau]; later Hend0 [p][n]
    __shared__ __align__(16) ushort sS [64 * LS];   // [t][tau]; later Yint [t][p]
    __shared__ float sSa[64], sSb[64], sW[64];

    const int tid  = threadIdx.x, lane = tid & 63, w = tid >> 6;
    const int quad = lane >> 4,   l16  = lane & 15;
    const int blk = blockIdx.x;               // ((b*NC)+c)*H + h  (h fastest)
    const int h   = blk & (H - 1);
    const int c   = (blk >> 4) & (NC - 1);
    const int b   = blk >> 9;
    const int t0  = c * L;
    const int chunkid = (b * H + h) * NC + c;

    // stage B,C -> bf16 [t][n]
    {
        const float4* gB4 = (const float4*)(Bm + ((size_t)b * T + t0) * N);
        const float4* gC4 = (const float4*)(Cm + ((size_t)b * T + t0) * N);
        #pragma unroll
        for (int r = 0; r < 4; ++r) {
            int idx = r * 256 + tid, t = idx >> 4, n4 = (idx & 15) << 2;
            float4 vb = gB4[idx], vc = gC4[idx];
            *(uint2*)&sB[t * LS + n4] = make_uint2(pack2(vb.x, vb.y), pack2(vb.z, vb.w));
            *(uint2*)&sC[t * LS + n4] = make_uint2(pack2(vc.x, vc.y), pack2(vc.z, vc.w));
        }
        const float* gB = Bm + ((size_t)b * T + t0) * N;
        #pragma unroll
        for (int i = 0; i < 8; ++i) {
            int tau = (w * 8 + i) * 2;
            *(unsigned*)&sBt[lane * LS + tau] =
                pack2(gB[(size_t)tau * N + lane], gB[(size_t)(tau + 1) * N + lane]);
        }
    }
    // transpose X (this h) -> [p][tau]
    {
        const float* gX = X + (((size_t)b * T + t0) * H + h) * P;
        #pragma unroll
        for (int i = 0; i < 8; ++i) {
            int tau = w * 16 + 2 * i;
            *(unsigned*)&sXt[lane * LS + tau] =
                pack2(gX[(size_t)tau * (H * P) + lane],
                      gX[(size_t)(tau + 1) * (H * P) + lane]);
        }
    }
    if (w == 0) {
        float dl = delta[((size_t)b * T + t0 + lane) * H + h];
        float s = -__expf(A_log[h]) * dl;
        #pragma unroll
        for (int off = 1; off < 64; off <<= 1) {
            float u = __shfl_up(s, off, 64);
            if (lane >= off) s += u;
        }
        float sL  = __shfl(s, 63, 64);
        float lnd = __logf(dl);
        sSa[lane] = s;
        sSb[lane] = lnd - s;
        sW [lane] = __expf(sL + lnd - s);
        if (lane == 63) Dchunk[chunkid] = __expf(sL);
    }
    __syncthreads();

    // G strip (rows t in [16w,16w+16))
    f32x4 g[4];
    #pragma unroll
    for (int j = 0; j < 4; ++j) g[j] = (f32x4){0.f, 0.f, 0.f, 0.f};
    #pragma unroll
    for (int ks = 0; ks < 2; ++ks) {
        const int ko = ks * 32 + quad * 8;
        bf16x8 af = *(const bf16x8*)&sC[(w * 16 + l16) * LS + ko];
        #pragma unroll
        for (int jt = 0; jt < 4; ++jt) {
            bf16x8 bfr = *(const bf16x8*)&sB[(jt * 16 + l16) * LS + ko];
            g[jt] = __builtin_amdgcn_mfma_f32_16x16x32_bf16(af, bfr, g[jt], 0, 0, 0);
        }
    }
    // S strip -> bf16 LDS
    #pragma unroll
    for (int jt = 0; jt < 4; ++jt) {
        const int tau = jt * 16 + l16;
        const float sbv = sSb[tau];
        #pragma unroll
        for (int r = 0; r < 4; ++r) {
            const int t = w * 16 + quad * 4 + r;
            float arg = (tau <= t) ? (sSa[t] + sbv) : -80.0f;
            sS[t * LS + tau] = f2bf(__expf(arg) * g[jt][r]);
        }
    }
    __syncthreads();

    // Yint strip = S.X^T  and  Hend0 strip = (w*X)^T.B
    f32x4 ya[4], ha[4];
    #pragma unroll
    for (int j = 0; j < 4; ++j) {
        ya[j] = (f32x4){0.f, 0.f, 0.f, 0.f};
        ha[j] = (f32x4){0.f, 0.f, 0.f, 0.f};
    }
    #pragma unroll
    for (int ks = 0; ks < 2; ++ks) {
        const int ko = ks * 32 + quad * 8;
        bf16x8 sa = *(const bf16x8*)&sS [(w * 16 + l16) * LS + ko];
        bf16x8 xa = *(const bf16x8*)&sXt[(w * 16 + l16) * LS + ko];
        union { bf16x8 v; unsigned u[4]; } xw;
        #pragma unroll
        for (int j2 = 0; j2 < 4; ++j2)
            xw.u[j2] = pack2(bf2f((ushort)xa[2*j2])   * sW[ko + 2*j2],
                             bf2f((ushort)xa[2*j2+1]) * sW[ko + 2*j2+1]);
        #pragma unroll
        for (int jp = 0; jp < 4; ++jp) {
            bf16x8 xb = *(const bf16x8*)&sXt[(jp * 16 + l16) * LS + ko];
            ya[jp] = __builtin_amdgcn_mfma_f32_16x16x32_bf16(sa, xb, ya[jp], 0, 0, 0);
        }
        #pragma unroll
        for (int jn = 0; jn < 4; ++jn) {
            bf16x8 bb = *(const bf16x8*)&sBt[(jn * 16 + l16) * LS + ko];
            ha[jn] = __builtin_amdgcn_mfma_f32_16x16x32_bf16(xw.v, bb, ha[jn], 0, 0, 0);
        }
    }

    // Restage results into (now dead) sS/sXt, then coalesced packed stores.
    __syncthreads();   // everyone done reading sXt/sS/sBt
    #pragma unroll
    for (int jp = 0; jp < 4; ++jp)
        #pragma unroll
        for (int r = 0; r < 4; ++r)
            sS[(w * 16 + quad * 4 + r) * LS + jp * 16 + l16] = f2bf(ya[jp][r]);
    #pragma unroll
    for (int jn = 0; jn < 4; ++jn)
        #pragma unroll
        for (int r = 0; r < 4; ++r)
            sXt[(w * 16 + quad * 4 + r) * LS + jn * 16 + l16] = f2bf(ha[jn][r]);
    __syncthreads();
    ushort* Yt = Ybuf + (size_t)chunkid * 4096;   // [t][p] packed bf16
    ushort* Ht = Hbuf + (size_t)chunkid * 4096;   // [p][n] packed bf16
    #pragma unroll
    for (int i = 0; i < 2; ++i) {
        int j = i * 256 + tid, t = j >> 3, col = (j & 7) * 8;
        *(uint4*)&Yt[j * 8] = *(const uint4*)&sS [t * LS + col];
        *(uint4*)&Ht[j * 8] = *(const uint4*)&sXt[t * LS + col];
    }
}

// ---------------- P2: chunk scan over bf16 pairs ----------------
__global__ __launch_bounds__(256, 4) void p2_scan(
    const float* __restrict__ Dchunk, ushort* __restrict__ Hbuf,
    float* __restrict__ Hlast)
{
    const unsigned gid = blockIdx.x * 256u + threadIdx.x;   // 65536
    const int bh  = gid >> 11;              // wave-uniform (8 blocks per bh)
    const int rem = gid & 2047;             // uint index within tile
    unsigned* Hb = (unsigned*)Hbuf;
    unsigned v[NC];
    #pragma unroll
    for (int cc = 0; cc < NC; ++cc)
        v[cc] = Hb[(size_t)(bh * NC + cc) * 2048 + rem];
    float hx = 0.f, hy = 0.f;
    #pragma unroll
    for (int cc = 0; cc < NC; ++cc) {
        const float lo = bf2f((ushort)(v[cc] & 0xffffu));
        const float hi = bf2f((ushort)(v[cc] >> 16));
        v[cc] = pack2(hx, hy);              // Hstart for chunk cc
        const float D = Dchunk[bh * NC + cc];
        hx = D * hx + lo;
        hy = D * hy + hi;
    }
    #pragma unroll
    for (int cc = 0; cc < NC; ++cc)
        Hb[(size_t)(bh * NC + cc) * 2048 + rem] = v[cc];
    ((float2*)Hlast)[gid] = make_float2(hx, hy);
}

// ---------------- P3: Y = Yint + Lambda_t * C . Hstart ----------------
__global__ __launch_bounds__(256, 3) void p3_inter(
    const float* __restrict__ delta, const float* __restrict__ Cm,
    const float* __restrict__ A_log, const ushort* __restrict__ Hbuf,
    const ushort* __restrict__ Ybuf, float* __restrict__ Y)
{
    __shared__ __align__(16) ushort sC [64 * LS];   // [t][n] bf16
    __shared__ __align__(16) ushort sH [64 * LS];   // [p][n] bf16
    __shared__ __align__(16) ushort sYi[64 * LS];   // [t][p] bf16
    __shared__ __align__(16) float  sF [64 * FS];   // [t][p] fp32
    __shared__ float sLam[64];

    const int tid  = threadIdx.x, lane = tid & 63, w = tid >> 6;
    const int quad = lane >> 4,   l16  = lane & 15;
    const int blk = blockIdx.x;
    const int h   = blk & (H - 1);
    const int c   = (blk >> 4) & (NC - 1);
    const int b   = blk >> 9;
    const int t0  = c * L;
    const int chunkid = (b * H + h) * NC + c;

    {
        const float4* gC4 = (const float4*)(Cm + ((size_t)b * T + t0) * N);
        #pragma unroll
        for (int r = 0; r < 4; ++r) {
            int idx = r * 256 + tid, t = idx >> 4, n4 = (idx & 15) << 2;
            float4 vc = gC4[idx];
            *(uint2*)&sC[t * LS + n4] = make_uint2(pack2(vc.x, vc.y), pack2(vc.z, vc.w));
        }
        const uint4* Hg4 = (const uint4*)(Hbuf + (size_t)chunkid * 4096);
        const uint4* Yg4 = (const uint4*)(Ybuf + (size_t)chunkid * 4096);
        #pragma unroll
        for (int i = 0; i < 2; ++i) {
            int j = i * 256 + tid, t = j >> 3, col = (j & 7) * 8;
            *(uint4*)&sH [t * LS + col] = Hg4[j];
            *(uint4*)&sYi[t * LS + col] = Yg4[j];
        }
    }
    if (w == 0) {
        float dl = delta[((size_t)b * T + t0 + lane) * H + h];
        float s = -__expf(A_log[h]) * dl;
        #pragma unroll
        for (int off = 1; off < 64; off <<= 1) {
            float u = __shfl_up(s, off, 64);
            if (lane >= off) s += u;
        }
        sLam[lane] = __expf(s);
    }
    __syncthreads();

    f32x4 acc[4];
    #pragma unroll
    for (int j = 0; j < 4; ++j) acc[j] = (f32x4){0.f, 0.f, 0.f, 0.f};
    #pragma unroll
    for (int ks = 0; ks < 2; ++ks) {
        const int ko = ks * 32 + quad * 8;
        bf16x8 ca = *(const bf16x8*)&sC[(w * 16 + l16) * LS + ko];
        #pragma unroll
        for (int jp = 0; jp < 4; ++jp) {
            bf16x8 hb = *(const bf16x8*)&sH[(jp * 16 + l16) * LS + ko];
            acc[jp] = __builtin_amdgcn_mfma_f32_16x16x32_bf16(ca, hb, acc[jp], 0, 0, 0);
        }
    }

    // combine into fp32 LDS tile [t][p]
    #pragma unroll
    for (int jp = 0; jp < 4; ++jp)
        #pragma unroll
        for (int r = 0; r < 4; ++r) {
            const int t = w * 16 + quad * 4 + r;
            const int p = jp * 16 + l16;
            sF[t * FS + p] = bf2f(sYi[t * LS + p]) + sLam[t] * acc[jp][r];
        }
    __syncthreads();

    // coalesced Y store: 4 x (4 rows x 256B full-row segments)
    float* Yg = Y + (((size_t)b * T + t0) * H + h) * P;
    #pragma unroll
    for (int i = 0; i < 4; ++i) {
        int j = i * 256 + tid, t = j >> 4, c4 = j & 15;
        *(float4*)(Yg + (size_t)t * (H * P) + c4 * 4) =
            *(const float4*)&sF[t * FS + c4 * 4];
    }
}

extern "C" void kernel_launch(void* const* d_in, const int* in_sizes, int n_in,
                              void* d_out, int out_size, void* d_ws, size_t ws_size,
                              hipStream_t stream) {
    const float* X     = (const float*)d_in[0];
    const float* delta = (const float*)d_in[1];
    const float* Bm    = (const float*)d_in[2];
    const float* Cm    = (const float*)d_in[3];
    const float* A_log = (const float*)d_in[4];

    float* Y     = (float*)d_out;
    float* Hlast = (float*)d_out + (size_t)BSZ * T * H * P;

    constexpr size_t TILE = 4096;                       // elements per tile
    constexpr size_t NTILE = (size_t)BSZ * H * NC;      // 1024
    ushort* Hbuf = (ushort*)d_ws;                       // 8 MiB
    ushort* Ybuf = (ushort*)d_ws + NTILE * TILE;        // 8 MiB
    float* Dchunk = (float*)((char*)d_ws + 2 * NTILE * TILE * sizeof(ushort));

    const int nblk = BSZ * NC * H;   // 1024
    p1_intra<<<nblk, 256, 0, stream>>>(X, delta, Bm, Cm, A_log, Ybuf, Hbuf, Dchunk);
    p2_scan<<<(BSZ * H * P * N / 2) / 256, 256, 0, stream>>>(Dchunk, Hbuf, Hlast);
    p3_inter<<<nblk, 256, 0, stream>>>(delta, Cm, A_log, Hbuf, Ybuf, Y);
}

// Round 8
// 99.554 us; speedup vs baseline: 1.8818x; 1.0079x over previous
//
#include <hip/hip_runtime.h>

// Mamba-2 chunked SSD, round 8: Yint never leaves registers.
//   K1 (light): per (b,h,c): Hend0 = (w.X)^T . B  -> Hbuf bf16 tile.
//   K2: 32-chunk scan over bf16 pairs -> Hstart in place + Hlast (fp32).
//   K3 (heavy): G=C.B^T -> S=mask*exp*G (aliased over B tile) ->
//               Yint=S.X (regs) -> stage Hstart (prefetched at entry) ->
//               acc=C.Hstart -> Y = Yint + Lambda*acc  (single store).
// LDS aliasing keeps K3 at 3 tiles (~29 KB); __launch_bounds__(256,4) gives
// 4 blocks/CU on both heavy kernels (VGPR<=128).
// MFMA 16x16x32 bf16: A m=lane&15,k=quad*8+j; B n=lane&15,k=quad*8+j;
//                     D col=lane&15, row=quad*4+reg.
// LDS rows padded to 72 bf16 (36 words) to spread b128 reads over banks.
// NOTE: ~47 us of dur_us is the harness's 256 MiB d_ws poison fill
// (measured r4/r6/r7); kernel-side floor is ~15 us of HBM traffic.

constexpr int BSZ = 2, T = 2048, H = 16, P = 64, N = 64;
constexpr int L = 64, NC = T / L;   // 32 chunks
constexpr int LS = 72;              // LDS row stride (ushorts)

using bf16x8 = __attribute__((ext_vector_type(8))) short;
using f32x4  = __attribute__((ext_vector_type(4))) float;

__device__ inline ushort f2bf(float f) {
    unsigned u = __float_as_uint(f);
    u += 0x7FFFu + ((u >> 16) & 1u);
    return (ushort)(u >> 16);
}
__device__ inline unsigned pack2(float a, float b) {
    return (unsigned)f2bf(a) | ((unsigned)f2bf(b) << 16);
}
__device__ inline float bf2f(ushort h) {
    return __uint_as_float(((unsigned)h) << 16);
}

// ---------------- K1: chunk-local end state only ----------------
__global__ __launch_bounds__(256, 4) void k1_hend(
    const float* __restrict__ X, const float* __restrict__ delta,
    const float* __restrict__ Bm, const float* __restrict__ A_log,
    ushort* __restrict__ Hbuf, float* __restrict__ Dchunk)
{
    __shared__ __align__(16) ushort sBt[64 * LS];   // [n][tau]; later Hend [p][n]
    __shared__ __align__(16) ushort sXt[64 * LS];   // [p][tau]
    __shared__ float sWf[64];

    const int tid  = threadIdx.x, lane = tid & 63, w = tid >> 6;
    const int quad = lane >> 4,   l16  = lane & 15;
    const int blk = blockIdx.x;               // ((b*NC)+c)*H + h  (h fastest)
    const int h   = blk & (H - 1);
    const int c   = (blk >> 4) & (NC - 1);
    const int b   = blk >> 9;
    const int t0  = c * L;
    const int chunkid = (b * H + h) * NC + c;

    {   // B^T [n][tau]
        const float* gB = Bm + ((size_t)b * T + t0) * N;
        #pragma unroll
        for (int i = 0; i < 8; ++i) {
            int tau = (w * 8 + i) * 2;
            *(unsigned*)&sBt[lane * LS + tau] =
                pack2(gB[(size_t)tau * N + lane], gB[(size_t)(tau + 1) * N + lane]);
        }
    }
    {   // X^T [p][tau]
        const float* gX = X + (((size_t)b * T + t0) * H + h) * P;
        #pragma unroll
        for (int i = 0; i < 8; ++i) {
            int tau = w * 16 + 2 * i;
            *(unsigned*)&sXt[lane * LS + tau] =
                pack2(gX[(size_t)tau * (H * P) + lane],
                      gX[(size_t)(tau + 1) * (H * P) + lane]);
        }
    }
    if (w == 0) {
        float dl = delta[((size_t)b * T + t0 + lane) * H + h];
        float s = -__expf(A_log[h]) * dl;
        #pragma unroll
        for (int off = 1; off < 64; off <<= 1) {
            float u = __shfl_up(s, off, 64);
            if (lane >= off) s += u;
        }
        float sL = __shfl(s, 63, 64);
        sWf[lane] = __expf(sL + __logf(dl) - s);
        if (lane == 63) Dchunk[chunkid] = __expf(sL);
    }
    __syncthreads();

    f32x4 ha[4];
    #pragma unroll
    for (int j = 0; j < 4; ++j) ha[j] = (f32x4){0.f, 0.f, 0.f, 0.f};
    #pragma unroll
    for (int ks = 0; ks < 2; ++ks) {
        const int ko = ks * 32 + quad * 8;
        bf16x8 xa = *(const bf16x8*)&sXt[(w * 16 + l16) * LS + ko];
        union { bf16x8 v; unsigned u[4]; } xw;
        #pragma unroll
        for (int j2 = 0; j2 < 4; ++j2)
            xw.u[j2] = pack2(bf2f((ushort)xa[2*j2])   * sWf[ko + 2*j2],
                             bf2f((ushort)xa[2*j2+1]) * sWf[ko + 2*j2+1]);
        #pragma unroll
        for (int jn = 0; jn < 4; ++jn) {
            bf16x8 bb = *(const bf16x8*)&sBt[(jn * 16 + l16) * LS + ko];
            ha[jn] = __builtin_amdgcn_mfma_f32_16x16x32_bf16(xw.v, bb, ha[jn], 0, 0, 0);
        }
    }
    __syncthreads();   // all sBt/sXt reads done
    #pragma unroll
    for (int jn = 0; jn < 4; ++jn)
        #pragma unroll
        for (int r = 0; r < 4; ++r)
            sBt[(w * 16 + quad * 4 + r) * LS + jn * 16 + l16] = f2bf(ha[jn][r]);
    __syncthreads();
    ushort* Ht = Hbuf + (size_t)chunkid * 4096;   // [p][n] packed bf16
    #pragma unroll
    for (int i = 0; i < 2; ++i) {
        int j = i * 256 + tid, t = j >> 3, col = (j & 7) * 8;
        *(uint4*)&Ht[j * 8] = *(const uint4*)&sBt[t * LS + col];
    }
}

// ---------------- K2: chunk scan over bf16 pairs ----------------
__global__ __launch_bounds__(256, 4) void k2_scan(
    const float* __restrict__ Dchunk, ushort* __restrict__ Hbuf,
    float* __restrict__ Hlast)
{
    const unsigned gid = blockIdx.x * 256u + threadIdx.x;   // 65536
    const int bh  = gid >> 11;
    const int rem = gid & 2047;
    unsigned* Hb = (unsigned*)Hbuf;
    unsigned v[NC];
    #pragma unroll
    for (int cc = 0; cc < NC; ++cc)
        v[cc] = Hb[(size_t)(bh * NC + cc) * 2048 + rem];
    float hx = 0.f, hy = 0.f;
    #pragma unroll
    for (int cc = 0; cc < NC; ++cc) {
        const float lo = bf2f((ushort)(v[cc] & 0xffffu));
        const float hi = bf2f((ushort)(v[cc] >> 16));
        v[cc] = pack2(hx, hy);              // Hstart for chunk cc
        const float D = Dchunk[bh * NC + cc];
        hx = D * hx + lo;
        hy = D * hy + hi;
    }
    #pragma unroll
    for (int cc = 0; cc < NC; ++cc)
        Hb[(size_t)(bh * NC + cc) * 2048 + rem] = v[cc];
    ((float2*)Hlast)[gid] = make_float2(hx, hy);
}

// ---------------- K3: Y = Yint + Lambda * C . Hstart ----------------
__global__ __launch_bounds__(256, 4) void k3_y(
    const float* __restrict__ X, const float* __restrict__ delta,
    const float* __restrict__ Bm, const float* __restrict__ Cm,
    const float* __restrict__ A_log, const ushort* __restrict__ Hbuf,
    float* __restrict__ Y)
{
    __shared__ __align__(16) ushort sB [64 * LS];   // B [tau][n]; then S [t][tau]
    __shared__ __align__(16) ushort sC [64 * LS];   // C [t][n] (live throughout)
    __shared__ __align__(16) ushort sXt[64 * LS];   // X^T [p][tau]; then H [p][n]
    __shared__ float sSa[64], sSb[64], sLam[64];

    const int tid  = threadIdx.x, lane = tid & 63, w = tid >> 6;
    const int quad = lane >> 4,   l16  = lane & 15;
    const int blk = blockIdx.x;
    const int h   = blk & (H - 1);
    const int c   = (blk >> 4) & (NC - 1);
    const int b   = blk >> 9;
    const int t0  = c * L;
    const int chunkid = (b * H + h) * NC + c;

    // prefetch Hstart tile into regs (used in phase 5; latency fully hidden)
    uint4 hreg[2];
    {
        const uint4* Hg4 = (const uint4*)(Hbuf + (size_t)chunkid * 4096);
        hreg[0] = Hg4[tid];
        hreg[1] = Hg4[256 + tid];
    }
    {   // B,C natural [t][n]
        const float4* gB4 = (const float4*)(Bm + ((size_t)b * T + t0) * N);
        const float4* gC4 = (const float4*)(Cm + ((size_t)b * T + t0) * N);
        #pragma unroll
        for (int r = 0; r < 4; ++r) {
            int idx = r * 256 + tid, t = idx >> 4, n4 = (idx & 15) << 2;
            float4 vb = gB4[idx], vc = gC4[idx];
            *(uint2*)&sB[t * LS + n4] = make_uint2(pack2(vb.x, vb.y), pack2(vb.z, vb.w));
            *(uint2*)&sC[t * LS + n4] = make_uint2(pack2(vc.x, vc.y), pack2(vc.z, vc.w));
        }
    }
    {   // X^T [p][tau]
        const float* gX = X + (((size_t)b * T + t0) * H + h) * P;
        #pragma unroll
        for (int i = 0; i < 8; ++i) {
            int tau = w * 16 + 2 * i;
            *(unsigned*)&sXt[lane * LS + tau] =
                pack2(gX[(size_t)tau * (H * P) + lane],
                      gX[(size_t)(tau + 1) * (H * P) + lane]);
        }
    }
    if (w == 0) {
        float dl = delta[((size_t)b * T + t0 + lane) * H + h];
        float s = -__expf(A_log[h]) * dl;
        #pragma unroll
        for (int off = 1; off < 64; off <<= 1) {
            float u = __shfl_up(s, off, 64);
            if (lane >= off) s += u;
        }
        sSa[lane]  = s;
        sSb[lane]  = __logf(dl) - s;
        sLam[lane] = __expf(s);
    }
    __syncthreads();

    // G strip = C . B^T  (rows t in [16w,16w+16), K=n)
    f32x4 g[4];
    #pragma unroll
    for (int j = 0; j < 4; ++j) g[j] = (f32x4){0.f, 0.f, 0.f, 0.f};
    #pragma unroll
    for (int ks = 0; ks < 2; ++ks) {
        const int ko = ks * 32 + quad * 8;
        bf16x8 af = *(const bf16x8*)&sC[(w * 16 + l16) * LS + ko];
        #pragma unroll
        for (int jt = 0; jt < 4; ++jt) {
            bf16x8 bfr = *(const bf16x8*)&sB[(jt * 16 + l16) * LS + ko];
            g[jt] = __builtin_amdgcn_mfma_f32_16x16x32_bf16(af, bfr, g[jt], 0, 0, 0);
        }
    }
    __syncthreads();   // all G reads of sB done before S overwrites it

    // S strip -> sB alias [t][tau]
    #pragma unroll
    for (int jt = 0; jt < 4; ++jt) {
        const int tau = jt * 16 + l16;
        const float sbv = sSb[tau];
        #pragma unroll
        for (int r = 0; r < 4; ++r) {
            const int t = w * 16 + quad * 4 + r;
            float arg = (tau <= t) ? (sSa[t] + sbv) : -80.0f;
            sB[t * LS + tau] = f2bf(__expf(arg) * g[jt][r]);
        }
    }
    __syncthreads();

    // Yint strip = S . X  (regs only)
    f32x4 ya[4];
    #pragma unroll
    for (int j = 0; j < 4; ++j) ya[j] = (f32x4){0.f, 0.f, 0.f, 0.f};
    #pragma unroll
    for (int ks = 0; ks < 2; ++ks) {
        const int ko = ks * 32 + quad * 8;
        bf16x8 sa = *(const bf16x8*)&sB[(w * 16 + l16) * LS + ko];
        #pragma unroll
        for (int jp = 0; jp < 4; ++jp) {
            bf16x8 xb = *(const bf16x8*)&sXt[(jp * 16 + l16) * LS + ko];
            ya[jp] = __builtin_amdgcn_mfma_f32_16x16x32_bf16(sa, xb, ya[jp], 0, 0, 0);
        }
    }
    __syncthreads();   // all Yint reads of sXt done before H overwrites it

    // stage Hstart (from prefetched regs) -> sXt alias [p][n]
    #pragma unroll
    for (int i = 0; i < 2; ++i) {
        int j = i * 256 + tid, t = j >> 3, col = (j & 7) * 8;
        *(uint4*)&sXt[t * LS + col] = hreg[i];
    }
    __syncthreads();

    // inter strip: acc = C . Hstart^T  (D[t][p], K=n)
    f32x4 acc[4];
    #pragma unroll
    for (int j = 0; j < 4; ++j) acc[j] = (f32x4){0.f, 0.f, 0.f, 0.f};
    #pragma unroll
    for (int ks = 0; ks < 2; ++ks) {
        const int ko = ks * 32 + quad * 8;
        bf16x8 ca = *(const bf16x8*)&sC[(w * 16 + l16) * LS + ko];
        #pragma unroll
        for (int jp = 0; jp < 4; ++jp) {
            bf16x8 hb = *(const bf16x8*)&sXt[(jp * 16 + l16) * LS + ko];
            acc[jp] = __builtin_amdgcn_mfma_f32_16x16x32_bf16(ca, hb, acc[jp], 0, 0, 0);
        }
    }

    // single fused Y store (D-layout: 4 x 64B row segments per store)
    float* Yg = Y + (((size_t)b * T + t0) * H + h) * P;
    #pragma unroll
    for (int jp = 0; jp < 4; ++jp)
        #pragma unroll
        for (int r = 0; r < 4; ++r) {
            const int t = w * 16 + quad * 4 + r;
            Yg[(size_t)t * (H * P) + jp * 16 + l16] =
                ya[jp][r] + sLam[t] * acc[jp][r];
        }
}

extern "C" void kernel_launch(void* const* d_in, const int* in_sizes, int n_in,
                              void* d_out, int out_size, void* d_ws, size_t ws_size,
                              hipStream_t stream) {
    const float* X     = (const float*)d_in[0];
    const float* delta = (const float*)d_in[1];
    const float* Bm    = (const float*)d_in[2];
    const float* Cm    = (const float*)d_in[3];
    const float* A_log = (const float*)d_in[4];

    float* Y     = (float*)d_out;
    float* Hlast = (float*)d_out + (size_t)BSZ * T * H * P;

    constexpr size_t TILE = 4096;                    // elements per tile
    constexpr size_t NTILE = (size_t)BSZ * H * NC;   // 1024
    ushort* Hbuf  = (ushort*)d_ws;                   // 8 MiB
    float* Dchunk = (float*)((char*)d_ws + NTILE * TILE * sizeof(ushort));

    const int nblk = BSZ * NC * H;   // 1024
    k1_hend<<<nblk, 256, 0, stream>>>(X, delta, Bm, A_log, Hbuf, Dchunk);
    k2_scan<<<(BSZ * H * P * N / 2) / 256, 256, 0, stream>>>(Dchunk, Hbuf, Hlast);
    k3_y<<<nblk, 256, 0, stream>>>(X, delta, Bm, Cm, A_log, Hbuf, Y);
}

// Round 9
// 95.546 us; speedup vs baseline: 1.9608x; 1.0419x over previous
//
#include <hip/hip_runtime.h>

// Round 9: DMA-staged Mamba-2 chunked SSD.
//   KA: per (b,h,c): build swizzled bf16 tiles (Xt [p][tau]) + cumsum vectors,
//       compute Hend0=(w.X)^T.B, dump Xt/Hend/Bbf/Cbf/Vec to ws.
//   K2: 32-chunk scan over bf16 pairs (layout-agnostic) -> Hstart + Hlast.
//   K3: stage C,B,Xt,Hstart via __builtin_amdgcn_global_load_lds (width 16,
//       1 KB/instr) -> G=C.B^T -> S=mask*exp*G (alias over B) ->
//       Yint=S.Xt + acc=C.Hst -> Y = Yint + Lam*acc (single store).
// Tile format: 64x64 bf16, UNPADDED, 16B-group XOR swizzle:
//   elem(row,col) stored at row*64 + ((col>>3 ^ (row&7))<<3) + (col&7).
//   -> ds_read_b128 frag reads hit 8 bank-groups x2 lanes (2-way = free, m136)
//   -> lane-contiguous rows, so global_load_lds DMA works (no padding allowed).
// MFMA 16x16x32 bf16: A m=lane&15,k=quad*8+j; B n=lane&15,k=quad*8+j;
//                     D col=lane&15, row=quad*4+reg.
// All MFMA frag rows are == l16 (mod 8), so swizzle group = (ko>>3)^(l16&7).

constexpr int BSZ = 2, T = 2048, H = 16, P = 64, N = 64;
constexpr int L = 64, NC = T / L;   // 32 chunks
constexpr int LSB = 72;             // padded stride for KA-internal B^T only

using bf16x8 = __attribute__((ext_vector_type(8))) short;
using f32x4  = __attribute__((ext_vector_type(4))) float;

__device__ inline ushort f2bf(float f) {
    unsigned u = __float_as_uint(f);
    u += 0x7FFFu + ((u >> 16) & 1u);
    return (ushort)(u >> 16);
}
__device__ inline unsigned pack2(float a, float b) {
    return (unsigned)f2bf(a) | ((unsigned)f2bf(b) << 16);
}
__device__ inline float bf2f(ushort h) {
    return __uint_as_float(((unsigned)h) << 16);
}
__device__ inline int swz(int row, int col) {   // element offset in 64x64 tile
    return row * 64 + ((((col >> 3) ^ (row & 7))) << 3) + (col & 7);
}

typedef __attribute__((address_space(3))) unsigned int       lds_u32;
typedef const __attribute__((address_space(1))) unsigned int glb_u32;
__device__ inline void dma16(const void* g, void* l) {   // 16B/lane -> 1KB/wave
    __builtin_amdgcn_global_load_lds((glb_u32*)g, (lds_u32*)l, 16, 0, 0);
}
__device__ inline void dma4(const void* g, void* l) {    // 4B/lane -> 256B/wave
    __builtin_amdgcn_global_load_lds((glb_u32*)g, (lds_u32*)l, 4, 0, 0);
}

// ---------------- KA: prep + chunk-local end state ----------------
__global__ __launch_bounds__(256, 4) void ka_prep(
    const float* __restrict__ X, const float* __restrict__ delta,
    const float* __restrict__ Bm, const float* __restrict__ Cm,
    const float* __restrict__ A_log,
    ushort* __restrict__ Xtg, ushort* __restrict__ Hbuf,
    ushort* __restrict__ Bbf, ushort* __restrict__ Cbf,
    float* __restrict__ Vec, float* __restrict__ Dchunk)
{
    __shared__ __align__(16) ushort sXt[4096];       // [p][tau] swizzled
    __shared__ __align__(16) ushort sBt[64 * LSB];   // [n][tau] padded (internal)
    __shared__ float sWf[64];

    const int tid  = threadIdx.x, lane = tid & 63, w = tid >> 6;
    const int quad = lane >> 4,   l16  = lane & 15;
    const int blk = blockIdx.x;               // ((b*NC)+c)*H + h  (h fastest)
    const int h   = blk & (H - 1);
    const int c   = (blk >> 4) & (NC - 1);
    const int b   = blk >> 9;
    const int t0  = c * L;
    const int chunkid = (b * H + h) * NC + c;
    const int bcid    = b * NC + c;

    {   // B^T [n][tau] (padded, KA-internal)
        const float* gB = Bm + ((size_t)b * T + t0) * N;
        #pragma unroll
        for (int i = 0; i < 8; ++i) {
            int tau = (w * 8 + i) * 2;
            *(unsigned*)&sBt[lane * LSB + tau] =
                pack2(gB[(size_t)tau * N + lane], gB[(size_t)(tau + 1) * N + lane]);
        }
    }
    {   // X^T [p][tau] swizzled
        const float* gX = X + (((size_t)b * T + t0) * H + h) * P;
        #pragma unroll
        for (int i = 0; i < 8; ++i) {
            int tau = w * 16 + 2 * i;
            *(unsigned*)&sXt[swz(lane, tau)] =
                pack2(gX[(size_t)tau * (H * P) + lane],
                      gX[(size_t)(tau + 1) * (H * P) + lane]);
        }
    }
    if (h == 0) {   // dump B,C bf16 swizzled tiles (once per (b,c))
        const float4* gB4 = (const float4*)(Bm + ((size_t)b * T + t0) * N);
        const float4* gC4 = (const float4*)(Cm + ((size_t)b * T + t0) * N);
        ushort* Bt = Bbf + (size_t)bcid * 4096;
        ushort* Ct = Cbf + (size_t)bcid * 4096;
        #pragma unroll
        for (int r = 0; r < 4; ++r) {
            int idx = r * 256 + tid, t = idx >> 4, n4 = idx & 15;
            int g = n4 >> 1, half = n4 & 1;
            int off = t * 64 + (((g ^ (t & 7))) << 3) + half * 4;
            float4 vb = gB4[idx], vc = gC4[idx];
            *(uint2*)&Bt[off] = make_uint2(pack2(vb.x, vb.y), pack2(vb.z, vb.w));
            *(uint2*)&Ct[off] = make_uint2(pack2(vc.x, vc.y), pack2(vc.z, vc.w));
        }
    }
    if (w == 0) {   // cumsum + vector dumps
        float dl = delta[((size_t)b * T + t0 + lane) * H + h];
        float s = -__expf(A_log[h]) * dl;
        #pragma unroll
        for (int off = 1; off < 64; off <<= 1) {
            float u = __shfl_up(s, off, 64);
            if (lane >= off) s += u;
        }
        float sL  = __shfl(s, 63, 64);
        float lnd = __logf(dl);
        sWf[lane] = __expf(sL + lnd - s);
        float* vp = Vec + (size_t)chunkid * 192;
        vp[lane]       = s;            // sa
        vp[64 + lane]  = lnd - s;      // sb
        vp[128 + lane] = __expf(s);    // Lambda
        if (lane == 63) Dchunk[chunkid] = __expf(sL);
    }
    __syncthreads();

    // Hend0 strip = (w*X)^T . B
    f32x4 ha[4];
    #pragma unroll
    for (int j = 0; j < 4; ++j) ha[j] = (f32x4){0.f, 0.f, 0.f, 0.f};
    #pragma unroll
    for (int ks = 0; ks < 2; ++ks) {
        const int ko = ks * 32 + quad * 8;
        const int sg = (ko >> 3) ^ (l16 & 7);
        bf16x8 xa = *(const bf16x8*)&sXt[(w * 16 + l16) * 64 + sg * 8];
        union { bf16x8 v; unsigned u[4]; } xw;
        #pragma unroll
        for (int j2 = 0; j2 < 4; ++j2)
            xw.u[j2] = pack2(bf2f((ushort)xa[2*j2])   * sWf[ko + 2*j2],
                             bf2f((ushort)xa[2*j2+1]) * sWf[ko + 2*j2+1]);
        #pragma unroll
        for (int jn = 0; jn < 4; ++jn) {
            bf16x8 bb = *(const bf16x8*)&sBt[(jn * 16 + l16) * LSB + ko];
            ha[jn] = __builtin_amdgcn_mfma_f32_16x16x32_bf16(xw.v, bb, ha[jn], 0, 0, 0);
        }
    }

    // dump Xt tile (linear copy; sXt fully written since pre-MFMA barrier)
    {
        ushort* Xtt = Xtg + (size_t)chunkid * 4096;
        #pragma unroll
        for (int i = 0; i < 2; ++i) {
            int j = i * 256 + tid;
            ((uint4*)Xtt)[j] = ((const uint4*)sXt)[j];
        }
    }
    __syncthreads();   // all sBt frag reads done
    // restage Hend swizzled into sBt area (unpadded addressing)
    {
        ushort* hst = sBt;
        #pragma unroll
        for (int jn = 0; jn < 4; ++jn)
            #pragma unroll
            for (int r = 0; r < 4; ++r)
                hst[swz(w * 16 + quad * 4 + r, jn * 16 + l16)] = f2bf(ha[jn][r]);
    }
    __syncthreads();
    {
        ushort* Ht = Hbuf + (size_t)chunkid * 4096;
        #pragma unroll
        for (int i = 0; i < 2; ++i) {
            int j = i * 256 + tid;
            ((uint4*)Ht)[j] = ((const uint4*)sBt)[j];
        }
    }
}

// ---------------- K2: chunk scan over bf16 pairs ----------------
__global__ __launch_bounds__(256, 4) void k2_scan(
    const float* __restrict__ Dchunk, ushort* __restrict__ Hbuf,
    float* __restrict__ Hlast)
{
    const unsigned gid = blockIdx.x * 256u + threadIdx.x;   // 65536
    const int bh  = gid >> 11;
    const int rem = gid & 2047;
    unsigned* Hb = (unsigned*)Hbuf;
    unsigned v[NC];
    #pragma unroll
    for (int cc = 0; cc < NC; ++cc)
        v[cc] = Hb[(size_t)(bh * NC + cc) * 2048 + rem];
    float hx = 0.f, hy = 0.f;
    #pragma unroll
    for (int cc = 0; cc < NC; ++cc) {
        const float lo = bf2f((ushort)(v[cc] & 0xffffu));
        const float hi = bf2f((ushort)(v[cc] >> 16));
        v[cc] = pack2(hx, hy);              // Hstart for chunk cc
        const float D = Dchunk[bh * NC + cc];
        hx = D * hx + lo;
        hy = D * hy + hi;
    }
    #pragma unroll
    for (int cc = 0; cc < NC; ++cc)
        Hb[(size_t)(bh * NC + cc) * 2048 + rem] = v[cc];
    // un-swizzle for Hlast [b,h,p,n]
    const int p   = rem >> 5, w32 = rem & 31;
    const int g   = (w32 >> 2) ^ (p & 7);
    const int n0  = (g << 3) + ((w32 & 3) << 1);
    *(float2*)&Hlast[(size_t)bh * 4096 + p * 64 + n0] = make_float2(hx, hy);
}

// ---------------- K3: Y = Yint + Lambda * C . Hstart ----------------
__global__ __launch_bounds__(256, 4) void k3_y(
    const ushort* __restrict__ Xtg, const ushort* __restrict__ Bbf,
    const ushort* __restrict__ Cbf, const float* __restrict__ Vec,
    const ushort* __restrict__ Hbuf, float* __restrict__ Y)
{
    __shared__ __align__(16) ushort sC [4096];   // C [t][n]
    __shared__ __align__(16) ushort sB [4096];   // B [tau][n]; then S [t][tau]
    __shared__ __align__(16) ushort sXt[4096];   // Xt [p][tau]
    __shared__ __align__(16) ushort sH [4096];   // Hstart [p][n]
    __shared__ float sVec[192];                  // sa | sb | Lambda

    const int tid  = threadIdx.x, lane = tid & 63, w = tid >> 6;
    const int quad = lane >> 4,   l16  = lane & 15;
    const int blk = blockIdx.x;
    const int h   = blk & (H - 1);
    const int c   = (blk >> 4) & (NC - 1);
    const int b   = blk >> 9;
    const int t0  = c * L;
    const int chunkid = (b * H + h) * NC + c;
    const int bcid    = b * NC + c;

    // DMA staging: wave w pulls one 8 KB tile (8 x 1 KB instrs)
    {
        const ushort* gsrc;
        ushort* ldst;
        if      (w == 0) { gsrc = Cbf + (size_t)bcid * 4096;    ldst = sC;  }
        else if (w == 1) { gsrc = Bbf + (size_t)bcid * 4096;    ldst = sB;  }
        else if (w == 2) { gsrc = Xtg + (size_t)chunkid * 4096; ldst = sXt; }
        else             { gsrc = Hbuf + (size_t)chunkid * 4096; ldst = sH; }
        const char* g = (const char*)gsrc + lane * 16;
        #pragma unroll
        for (int i = 0; i < 8; ++i)
            dma16(g + i * 1024, (char*)ldst + i * 1024);
        if (w == 0) {
            const float* vp = Vec + (size_t)chunkid * 192;
            dma4(vp + lane,       sVec);
            dma4(vp + 64 + lane,  sVec + 64);
            dma4(vp + 128 + lane, sVec + 128);
        }
    }
    __syncthreads();

    // G strip = C . B^T  (rows t in [16w,16w+16), K=n)
    f32x4 g4[4];
    #pragma unroll
    for (int j = 0; j < 4; ++j) g4[j] = (f32x4){0.f, 0.f, 0.f, 0.f};
    #pragma unroll
    for (int ks = 0; ks < 2; ++ks) {
        const int ko = ks * 32 + quad * 8;
        const int sg = (ko >> 3) ^ (l16 & 7);
        bf16x8 af = *(const bf16x8*)&sC[(w * 16 + l16) * 64 + sg * 8];
        #pragma unroll
        for (int jt = 0; jt < 4; ++jt) {
            bf16x8 bfr = *(const bf16x8*)&sB[(jt * 16 + l16) * 64 + sg * 8];
            g4[jt] = __builtin_amdgcn_mfma_f32_16x16x32_bf16(af, bfr, g4[jt], 0, 0, 0);
        }
    }
    __syncthreads();   // all G reads of sB done before S overwrites it

    // S strip -> sB alias (swizzled [t][tau])
    #pragma unroll
    for (int jt = 0; jt < 4; ++jt) {
        const int tau = jt * 16 + l16;
        const float sbv = sVec[64 + tau];
        #pragma unroll
        for (int r = 0; r < 4; ++r) {
            const int t = w * 16 + quad * 4 + r;
            float arg = (tau <= t) ? (sVec[t] + sbv) : -80.0f;
            sB[swz(t, tau)] = f2bf(__expf(arg) * g4[jt][r]);
        }
    }
    __syncthreads();

    // Yint = S . Xt  and  acc = C . Hstart
    f32x4 ya[4], acc[4];
    #pragma unroll
    for (int j = 0; j < 4; ++j) {
        ya[j]  = (f32x4){0.f, 0.f, 0.f, 0.f};
        acc[j] = (f32x4){0.f, 0.f, 0.f, 0.f};
    }
    #pragma unroll
    for (int ks = 0; ks < 2; ++ks) {
        const int ko = ks * 32 + quad * 8;
        const int sg = (ko >> 3) ^ (l16 & 7);
        bf16x8 sa = *(const bf16x8*)&sB[(w * 16 + l16) * 64 + sg * 8];
        bf16x8 ca = *(const bf16x8*)&sC[(w * 16 + l16) * 64 + sg * 8];
        #pragma unroll
        for (int jp = 0; jp < 4; ++jp) {
            bf16x8 xb = *(const bf16x8*)&sXt[(jp * 16 + l16) * 64 + sg * 8];
            bf16x8 hb = *(const bf16x8*)&sH [(jp * 16 + l16) * 64 + sg * 8];
            ya[jp]  = __builtin_amdgcn_mfma_f32_16x16x32_bf16(sa, xb, ya[jp], 0, 0, 0);
            acc[jp] = __builtin_amdgcn_mfma_f32_16x16x32_bf16(ca, hb, acc[jp], 0, 0, 0);
        }
    }

    // fused Y store (D-layout: 4 x 64B row segments per store)
    float* Yg = Y + (((size_t)b * T + t0) * H + h) * P;
    #pragma unroll
    for (int jp = 0; jp < 4; ++jp)
        #pragma unroll
        for (int r = 0; r < 4; ++r) {
            const int t = w * 16 + quad * 4 + r;
            Yg[(size_t)t * (H * P) + jp * 16 + l16] =
                ya[jp][r] + sVec[128 + t] * acc[jp][r];
        }
}

extern "C" void kernel_launch(void* const* d_in, const int* in_sizes, int n_in,
                              void* d_out, int out_size, void* d_ws, size_t ws_size,
                              hipStream_t stream) {
    const float* X     = (const float*)d_in[0];
    const float* delta = (const float*)d_in[1];
    const float* Bm    = (const float*)d_in[2];
    const float* Cm    = (const float*)d_in[3];
    const float* A_log = (const float*)d_in[4];

    float* Y     = (float*)d_out;
    float* Hlast = (float*)d_out + (size_t)BSZ * T * H * P;

    char* ws = (char*)d_ws;
    ushort* Hbuf = (ushort*)(ws);                          // 1024*8KB = 8 MiB
    ushort* Xtg  = (ushort*)(ws + (8u << 20));             // 8 MiB
    ushort* Bbf  = (ushort*)(ws + (16u << 20));            // 512 KiB
    ushort* Cbf  = (ushort*)(ws + (16u << 20) + (512u << 10));
    float*  Vec  = (float*)(ws + (17u << 20));             // 768 KiB
    float*  Dchunk = (float*)(ws + (18u << 20));           // 4 KiB

    const int nblk = BSZ * NC * H;   // 1024
    ka_prep<<<nblk, 256, 0, stream>>>(X, delta, Bm, Cm, A_log,
                                      Xtg, Hbuf, Bbf, Cbf, Vec, Dchunk);
    k2_scan<<<256, 256, 0, stream>>>(Dchunk, Hbuf, Hlast);
    k3_y<<<nblk, 256, 0, stream>>>(Xtg, Bbf, Cbf, Vec, Hbuf, Y);
}